// Round 9
// baseline (203.743 us; speedup 1.0000x reference)
//
#include <hip/hip_runtime.h>
#include <hip/hip_bf16.h>
#include <stdint.h>

// B=4, L=4096, D=1024, M_MAX=512
// out[b,l,e] = smoothed[b, pbi[b,l], e] + sum_d enc[b,l,d] * W[e,d]

#define B_  4
#define L_  4096
#define D_  1024
#define M_  512

typedef __attribute__((ext_vector_type(8))) short bf16x8;
typedef __attribute__((ext_vector_type(4))) float f32x4;
typedef __attribute__((ext_vector_type(8))) unsigned short u16x8;

__device__ inline unsigned short f2bf(float f) {
    unsigned u = __float_as_uint(f);
    u += 0x7fffu + ((u >> 16) & 1u);   // RNE
    return (unsigned short)(u >> 16);
}

// ============ prep_lite: W cvt + pbi + EMA (enc cvt ELIMINATED — fused into GEMM) ============
// blocks: [0,256) W f32->bf16 ; [256,260) pbi ; [260,324) EMA
__global__ void prep_lite_kernel(const float* __restrict__ W,
                                 const float* __restrict__ probs, const float* __restrict__ ct,
                                 const int* __restrict__ bidx,
                                 unsigned short* __restrict__ Wb,
                                 int* __restrict__ pbi, float* __restrict__ smoothed) {
    __shared__ int part[512];
    __shared__ float ad[M_], bdp[M_];
    __shared__ float Ac[8][64], Bc[8][64], Hin[8][64];

    const int blk = blockIdx.x;
    const int t   = threadIdx.x;

    if (blk < 256) {
        size_t i = (size_t)blk * 512 + t;
        float4 x0 = ((const float4*)W)[2 * i];
        float4 x1 = ((const float4*)W)[2 * i + 1];
        u16x8 v;
        v[0] = f2bf(x0.x); v[1] = f2bf(x0.y); v[2] = f2bf(x0.z); v[3] = f2bf(x0.w);
        v[4] = f2bf(x1.x); v[5] = f2bf(x1.y); v[6] = f2bf(x1.z); v[7] = f2bf(x1.w);
        ((u16x8*)Wb)[i] = v;
    } else if (blk < 260) {
        int b = blk - 256;
        const float4* pr = (const float4*)(probs + b * L_);
        int cnt[8]; int s = 0;
        #pragma unroll
        for (int u = 0; u < 2; ++u) {
            float4 x = pr[t * 2 + u];
            s += (x.x >= 0.5f); cnt[u * 4 + 0] = s;
            s += (x.y >= 0.5f); cnt[u * 4 + 1] = s;
            s += (x.z >= 0.5f); cnt[u * 4 + 2] = s;
            s += (x.w >= 0.5f); cnt[u * 4 + 3] = s;
        }
        part[t] = s;
        __syncthreads();
        for (int off = 1; off < 512; off <<= 1) {
            int x = part[t];
            int y = (t >= off) ? part[t - off] : 0;
            __syncthreads();
            part[t] = x + y;
            __syncthreads();
        }
        int excl = part[t] - s;
        int4* po = (int4*)(pbi + b * L_ + t * 8);
        #pragma unroll
        for (int u = 0; u < 2; ++u) {
            int4 o;
            o.x = max(excl + cnt[u * 4 + 0] - 1, 0);
            o.y = max(excl + cnt[u * 4 + 1] - 1, 0);
            o.z = max(excl + cnt[u * 4 + 2] - 1, 0);
            o.w = max(excl + cnt[u * 4 + 3] - 1, 0);
            po[u] = o;
        }
    } else {
        int idx = blk - 260;
        int b  = idx >> 4;
        int d0 = (idx & 15) * 64;
        int dl = t & 63;
        int ch = t >> 6;
        {
            int m = t;
            int bi = bidx[b * M_ + m];
            float p = fmaxf(probs[b * L_ + bi], 0.1f);
            ad[m]  = (m == 0) ? 0.0f : fmaxf(1.0f - p, 1e-7f);
            bdp[m] = (m == 0) ? 1.0f : p;
        }
        __syncthreads();
        const float* ctp = ct + ((size_t)b * M_ + ch * 64) * D_ + d0 + dl;
        float A = 1.0f, Bv = 0.0f;
        #pragma unroll 8
        for (int i = 0; i < 64; ++i) {
            int m = ch * 64 + i;
            float c = ctp[(size_t)i * D_];
            A  = ad[m] * A;
            Bv = ad[m] * Bv + bdp[m] * c;
        }
        Ac[ch][dl] = A; Bc[ch][dl] = Bv;
        __syncthreads();
        if (t < 64) {
            float H = 0.0f;
            #pragma unroll
            for (int c = 0; c < 8; ++c) {
                Hin[c][t] = H;
                H = Ac[c][t] * H + Bc[c][t];
            }
        }
        __syncthreads();
        float h = Hin[ch][dl];
        float* smp = smoothed + ((size_t)b * M_ + ch * 64) * D_ + d0 + dl;
        #pragma unroll 8
        for (int i = 0; i < 64; ++i) {
            int m = ch * 64 + i;
            float c = ctp[(size_t)i * D_];
            h = ad[m] * h + bdp[m] * c;
            smp[(size_t)i * D_] = h;
        }
    }
}

// ============ GEMM: 256x256, BK=64, 8-phase; A reg-staged (fp32->bf16 fused), B gload_lds ============
// LDS 128 KiB: A[db][half] at (db*2+h)*16384, B at 65536 + (db*2+h)*16384.
// Swizzle: col_byte ^= (row&7)<<4 on reads; A ds_writes + B global source pre-swizzled (rule #21).
// Per-iter vm-op order: ph1 A4, ph2 A4, ph3 B2, ph4 B2, ph5 A4, ph6 A4, ph7 B2, ph8 B2.
// vmcnt(2) at ph4/ph8 (leaves only own-phase B-pair) forces: cvt inputs (A), prev-iter B halves
// exactly before their first readers. A ds_writes published by next phase's lgkmcnt(0)+barrier.
#define NTT 16

__global__ __launch_bounds__(512, 2) void gemm8_kernel(
    const float* __restrict__ enc, const unsigned short* __restrict__ Wb,
    const float* __restrict__ smoothed, const int* __restrict__ pbi,
    float* __restrict__ out)
{
    __shared__ __align__(16) char smem[131072];

    const int tid  = threadIdx.x;
    const int lane = tid & 63;
    const int w    = tid >> 6;
    const int wm   = w >> 2;          // 0..1
    const int wn   = w & 3;           // 0..3
    const int l15  = lane & 15;
    const int l16  = lane >> 4;

    const int orig = blockIdx.x;
    const int rm   = (orig & 7) * 32 + (orig >> 3);
    const size_t rowBase = (size_t)(rm >> 2) * 256;
    const int    colBase = (rm & 3) * 256;

    // read-side swizzle
    const int rsw   = (l15 & 7) << 4;
    const int colb0 = (0  + l16 * 16) ^ rsw;
    const int colb1 = (64 + l16 * 16) ^ rsw;

    const int aRd0 = (0 + wm) * 16384 + l15 * 128;
    const int aRd1 = (2 + wm) * 16384 + l15 * 128;
    const int bRd0 = 65536 + (0 + (wn >> 1)) * 16384 + ((wn & 1) * 64 + l15) * 128;
    const int bRd1 = 65536 + (2 + (wn >> 1)) * 16384 + ((wn & 1) * 64 + l15) * 128;

    // ---- A reg-staging geometry: thread -> row arow (0..127 of half), 2 slots of 8 elems ----
    const int arow = tid >> 2;                 // 128 rows per half, 4 threads/row
    const int as0  = (tid & 3) * 2;            // first of 2 dest 16B slots
    const int asrc0 = ((as0    ) ^ (arow & 7)) * 8;   // source cols (pre-swizzled)
    const int asrc1 = ((as0 + 1) ^ (arow & 7)) * 8;
    const float* encA = enc + (rowBase + arow) * D_;  // fp32
    const int awr0 = arow * 128 + as0 * 16;           // dest bytes within half-region
    const int awr1 = arow * 128 + as0 * 16 + 16;

    // ---- B staging (gload_lds, unchanged) ----
    const int srow  = tid >> 3;
    const int sslot = (tid & 7) ^ ((tid >> 3) & 7);
    const unsigned short* bSrc = Wb + ((size_t)colBase + srow) * D_ + sslot * 8;

#define ISSUE_A(T, h, R, bank)                                                            \
  { const float* s_ = encA + (size_t)(h) * 128 * D_ + (T) * 64;                           \
    R[(bank)*4+0] = *(const float4*)(s_ + asrc0);                                         \
    R[(bank)*4+1] = *(const float4*)(s_ + asrc0 + 4);                                     \
    R[(bank)*4+2] = *(const float4*)(s_ + asrc1);                                         \
    R[(bank)*4+3] = *(const float4*)(s_ + asrc1 + 4); }

#define WRITE_A(db, h, R, bank)                                                           \
  { u16x8 w0, w1;                                                                         \
    w0[0]=f2bf(R[(bank)*4+0].x); w0[1]=f2bf(R[(bank)*4+0].y);                             \
    w0[2]=f2bf(R[(bank)*4+0].z); w0[3]=f2bf(R[(bank)*4+0].w);                             \
    w0[4]=f2bf(R[(bank)*4+1].x); w0[5]=f2bf(R[(bank)*4+1].y);                             \
    w0[6]=f2bf(R[(bank)*4+1].z); w0[7]=f2bf(R[(bank)*4+1].w);                             \
    w1[0]=f2bf(R[(bank)*4+2].x); w1[1]=f2bf(R[(bank)*4+2].y);                             \
    w1[2]=f2bf(R[(bank)*4+2].z); w1[3]=f2bf(R[(bank)*4+2].w);                             \
    w1[4]=f2bf(R[(bank)*4+3].x); w1[5]=f2bf(R[(bank)*4+3].y);                             \
    w1[6]=f2bf(R[(bank)*4+3].z); w1[7]=f2bf(R[(bank)*4+3].w);                             \
    *(u16x8*)(smem + ((db)*2+(h))*16384 + awr0) = w0;                                     \
    *(u16x8*)(smem + ((db)*2+(h))*16384 + awr1) = w1; }

#define STAGE_B(T, db, h)                                                                 \
  { _Pragma("unroll") for (int i_ = 0; i_ < 2; ++i_) {                                    \
      const unsigned short* g_ = bSrc + (size_t)((h) * 128 + i_ * 64) * D_ + (T) * 64;    \
      __builtin_amdgcn_global_load_lds(                                                   \
          (const __attribute__((address_space(1))) void*)g_,                              \
          (__attribute__((address_space(3))) void*)(smem + 65536 + ((db)*2+(h))*16384 + i_*8192 + tid*16), \
          16, 0, 0); } }

#define LDSA(aRd, mbase)                                                                  \
  { _Pragma("unroll") for (int m_ = 0; m_ < 4; ++m_) {                                    \
      a[m_*2+0] = *(const bf16x8*)(smem + (aRd) + ((mbase)+m_)*2048 + colb0);             \
      a[m_*2+1] = *(const bf16x8*)(smem + (aRd) + ((mbase)+m_)*2048 + colb1); } }

#define LDSB(bRd, nbase)                                                                  \
  { _Pragma("unroll") for (int n_ = 0; n_ < 2; ++n_) {                                    \
      b[((nbase)+n_)*2+0] = *(const bf16x8*)(smem + (bRd) + ((nbase)+n_)*2048 + colb0);   \
      b[((nbase)+n_)*2+1] = *(const bf16x8*)(smem + (bRd) + ((nbase)+n_)*2048 + colb1); } }

#define MFMA_Q(mbase, nbase)                                                              \
  { _Pragma("unroll") for (int m_ = 0; m_ < 4; ++m_)                                      \
    _Pragma("unroll") for (int n_ = 0; n_ < 2; ++n_) {                                    \
      acc[(mbase)+m_][(nbase)+n_] = __builtin_amdgcn_mfma_f32_16x16x32_bf16(              \
          a[m_*2+0], b[((nbase)+n_)*2+0], acc[(mbase)+m_][(nbase)+n_], 0, 0, 0);          \
      acc[(mbase)+m_][(nbase)+n_] = __builtin_amdgcn_mfma_f32_16x16x32_bf16(              \
          a[m_*2+1], b[((nbase)+n_)*2+1], acc[(mbase)+m_][(nbase)+n_], 0, 0, 0); } }

#define PH_OPEN()  do { __builtin_amdgcn_sched_barrier(0); __builtin_amdgcn_s_barrier();  \
    __builtin_amdgcn_sched_barrier(0);                                                    \
    asm volatile("s_waitcnt lgkmcnt(0)" ::: "memory");                                    \
    __builtin_amdgcn_sched_barrier(0); __builtin_amdgcn_s_setprio(1); } while (0)

#define PH_CLOSE() do { __builtin_amdgcn_s_setprio(0); __builtin_amdgcn_sched_barrier(0); \
    __builtin_amdgcn_s_barrier(); __builtin_amdgcn_sched_barrier(0); } while (0)

    f32x4 acc[8][4] = {};
    bf16x8 a[8], b[8];
    float4 ra[8], rb[8];

    // ---- prologue: A t0->db0, t1->db1 (reg cvt); B t0->db0, t1->db1 (gload_lds) ----
    ISSUE_A(0, 0, ra, 0); ISSUE_A(0, 1, ra, 1);
    ISSUE_A(1, 0, rb, 0); ISSUE_A(1, 1, rb, 1);
    STAGE_B(0, 0, 0); STAGE_B(0, 0, 1);
    STAGE_B(1, 1, 0); STAGE_B(1, 1, 1);
    WRITE_A(0, 0, ra, 0); WRITE_A(0, 1, ra, 1);   // compiler inserts vmcnt wait for ra use
    WRITE_A(1, 0, rb, 0); WRITE_A(1, 1, rb, 1);
    asm volatile("s_waitcnt vmcnt(0) lgkmcnt(0)" ::: "memory");
    __builtin_amdgcn_s_barrier();
    __builtin_amdgcn_sched_barrier(0);

    #pragma unroll 1
    for (int i = 0; i < NTT / 2; ++i) {
        const int t2 = (2 * i + 2 < NTT) ? 2 * i + 2 : NTT - 1;
        const int t3 = (2 * i + 3 < NTT) ? 2 * i + 3 : NTT - 1;
        // ph1: read db0 A(m0-3),B(n0-1) | issue A(t2,h0)
        LDSA(aRd0, 0); LDSB(bRd0, 0);
        ISSUE_A(t2, 0, ra, 0);
        PH_OPEN(); MFMA_Q(0, 0); PH_CLOSE();
        // ph2: read db0 B(n2-3) | issue A(t2,h1)
        LDSB(bRd0, 2);
        ISSUE_A(t2, 1, ra, 1);
        PH_OPEN(); MFMA_Q(0, 2); PH_CLOSE();
        // ph3: read db0 A(m4-7) | glds B(t2,h0)->db0
        LDSA(aRd0, 4);
        STAGE_B(t2, 0, 0);
        PH_OPEN(); MFMA_Q(4, 0); PH_CLOSE();
        // ph4: glds B(t2,h1)->db0 | vmcnt(2) | cvt+write A(t2)->db0
        STAGE_B(t2, 0, 1);
        asm volatile("s_waitcnt vmcnt(2)" ::: "memory");
        WRITE_A(0, 0, ra, 0); WRITE_A(0, 1, ra, 1);
        PH_OPEN(); MFMA_Q(4, 2); PH_CLOSE();
        // ph5: read db1 A(m0-3),B(n0-1) | issue A(t3,h0)
        LDSA(aRd1, 0); LDSB(bRd1, 0);
        ISSUE_A(t3, 0, ra, 0);
        PH_OPEN(); MFMA_Q(0, 0); PH_CLOSE();
        // ph6: read db1 B(n2-3) | issue A(t3,h1)
        LDSB(bRd1, 2);
        ISSUE_A(t3, 1, ra, 1);
        PH_OPEN(); MFMA_Q(0, 2); PH_CLOSE();
        // ph7: read db1 A(m4-7) | glds B(t3,h0)->db1
        LDSA(aRd1, 4);
        STAGE_B(t3, 1, 0);
        PH_OPEN(); MFMA_Q(4, 0); PH_CLOSE();
        // ph8: glds B(t3,h1)->db1 | vmcnt(2) | cvt+write A(t3)->db1
        STAGE_B(t3, 1, 1);
        asm volatile("s_waitcnt vmcnt(2)" ::: "memory");
        WRITE_A(1, 0, ra, 0); WRITE_A(1, 1, ra, 1);
        PH_OPEN(); MFMA_Q(4, 2); PH_CLOSE();
    }
#undef ISSUE_A
#undef WRITE_A
#undef STAGE_B
#undef LDSA
#undef LDSB
#undef MFMA_Q
#undef PH_OPEN
#undef PH_CLOSE

    // ---- epilogue: fused plugback gather + add, fp32 store ----
    #pragma unroll
    for (int m = 0; m < 8; ++m) {
        const size_t row0 = rowBase + wm * 128 + m * 16;
        #pragma unroll
        for (int j = 0; j < 4; ++j) {
            size_t row = row0 + l16 * 4 + j;
            int bb2 = (int)(row >> 12);
            int pb  = pbi[row];
            pb = pb < (M_ - 1) ? pb : (M_ - 1);
            const float* sm = smoothed + ((size_t)(bb2 * M_ + pb)) * D_;
            #pragma unroll
            for (int n = 0; n < 4; ++n) {
                int col = colBase + wn * 64 + n * 16 + l15;
                out[row * D_ + col] = acc[m][n][j] + sm[col];
            }
        }
    }
}

extern "C" void kernel_launch(void* const* d_in, const int* in_sizes, int n_in,
                              void* d_out, int out_size, void* d_ws, size_t ws_size,
                              hipStream_t stream) {
    const float* ct    = (const float*)d_in[0];
    const float* enc   = (const float*)d_in[1];
    const float* probs = (const float*)d_in[2];
    const int*   bidx  = (const int*)d_in[3];
    const float* W     = (const float*)d_in[5];
    float* out = (float*)d_out;
    char*  ws  = (char*)d_ws;

    const size_t SZ_SM  = (size_t)B_ * M_ * D_ * 4;   // 8 MiB
    const size_t SZ_PBI = (size_t)B_ * L_ * 4;        // 64 KiB
    float*          smoothed = (float*)ws;
    int*            pbi      = (int*)(ws + SZ_SM);
    unsigned short* Wb       = (unsigned short*)(ws + SZ_SM + SZ_PBI);

    hipLaunchKernelGGL(prep_lite_kernel, dim3(324), dim3(512), 0, stream,
                       W, probs, ct, bidx, Wb, pbi, smoothed);
    hipLaunchKernelGGL(gemm8_kernel, dim3(256), dim3(512), 0, stream,
                       enc, Wb, smoothed, pbi, out);
}